// Round 1
// baseline (10667.657 us; speedup 1.0000x reference)
//
#include <hip/hip_runtime.h>
#include <math.h>

#define TT 512
#define DD 768
#define NHH 12
#define NGG 4
#define HDD 64
#define FFF 2048
#define CCH 1536
#define SEQ 2048
#define NL 26
#define VOC 32000

// ---------------- helpers ----------------
__device__ __forceinline__ float fast_tanh(float x) {
    float e = __expf(2.0f * x);
    return 1.0f - 2.0f / (e + 1.0f);
}

// ---------------- rmsnorm: out = rms_norm(in, w) ----------------
__global__ __launch_bounds__(256) void rmsnorm_k(const float* __restrict__ in,
                                                 const float* __restrict__ w,
                                                 float* __restrict__ out) {
    int t = blockIdx.x, tid = threadIdx.x;
    const float* row = in + (size_t)t * DD;
    float x0 = row[tid], x1 = row[tid + 256], x2 = row[tid + 512];
    float s = x0 * x0 + x1 * x1 + x2 * x2;
#pragma unroll
    for (int o = 32; o > 0; o >>= 1) s += __shfl_xor(s, o);
    __shared__ float red[4];
    if ((tid & 63) == 0) red[tid >> 6] = s;
    __syncthreads();
    s = red[0] + red[1] + red[2] + red[3];
    float r = rsqrtf(s / 768.0f + 1e-6f);
    float* orow = out + (size_t)t * DD;
    orow[tid]       = x0 * r * (1.0f + w[tid]);
    orow[tid + 256] = x1 * r * (1.0f + w[tid + 256]);
    orow[tid + 512] = x2 * r * (1.0f + w[tid + 512]);
}

// ---------------- addnorm: h += rms_norm(in, w) ----------------
__global__ __launch_bounds__(256) void addnorm_k(float* __restrict__ h,
                                                 const float* __restrict__ in,
                                                 const float* __restrict__ w) {
    int t = blockIdx.x, tid = threadIdx.x;
    const float* row = in + (size_t)t * DD;
    float x0 = row[tid], x1 = row[tid + 256], x2 = row[tid + 512];
    float s = x0 * x0 + x1 * x1 + x2 * x2;
#pragma unroll
    for (int o = 32; o > 0; o >>= 1) s += __shfl_xor(s, o);
    __shared__ float red[4];
    if ((tid & 63) == 0) red[tid >> 6] = s;
    __syncthreads();
    s = red[0] + red[1] + red[2] + red[3];
    float r = rsqrtf(s / 768.0f + 1e-6f);
    float* hrow = h + (size_t)t * DD;
    hrow[tid]       += x0 * r * (1.0f + w[tid]);
    hrow[tid + 256] += x1 * r * (1.0f + w[tid + 256]);
    hrow[tid + 512] += x2 * r * (1.0f + w[tid + 512]);
}

// ------- qkv post: per-head rmsnorm (q,k) + rope, scatter q / kT / vfull -------
// qkv row layout: [g (4)][slot (5)][d (64)]; slots 0..2 = q heads, 3 = k, 4 = v
__global__ __launch_bounds__(256) void qkv_post(const float* __restrict__ qkv,
                                                const float* __restrict__ qnw,
                                                const float* __restrict__ knw,
                                                const float* __restrict__ cosp,
                                                const float* __restrict__ sinp,
                                                float* __restrict__ q,
                                                float* __restrict__ kfT,
                                                float* __restrict__ vf) {
    int tid = threadIdx.x;
    int lane = tid & 63, wid = tid >> 6;
    int sg = blockIdx.x * 4 + wid;           // 0 .. T*20-1
    int t = sg / 20, slot = sg % 20;
    int g = slot / 5, r = slot % 5;
    float v = qkv[(size_t)t * 1280 + slot * 64 + lane];
    if (r == 4) {  // v: raw copy into vfull[g][CCH+t][d]
        vf[((size_t)g * SEQ + CCH + t) * HDD + lane] = v;
        return;
    }
    float s = v * v;
#pragma unroll
    for (int o = 32; o > 0; o >>= 1) s += __shfl_xor(s, o);
    float nv = v * rsqrtf(s / 64.0f + 1e-6f);
    const float* wn = (r < 3) ? qnw : knw;
    nv *= (1.0f + wn[lane]);
    // rope: rot[d] = d<32 ? -x[d+32] : x[d-32]
    float other = __shfl_xor(nv, 32);
    float rot = (lane < 32) ? -other : other;
    float o = nv * cosp[t * 64 + lane] + rot * sinp[t * 64 + lane];
    if (r < 3)
        q[(((size_t)(g * 3 + r)) * TT + t) * HDD + lane] = o;
    else
        kfT[((size_t)g * HDD + lane) * SEQ + CCH + t] = o;  // scattered, small payload
}

// -------- transpose K cache [g][s][d] -> kT [g][d][s]  (cache part only) --------
__global__ __launch_bounds__(256) void build_kT(const float* __restrict__ kc,
                                                float* __restrict__ kfT) {
    int s0 = blockIdx.x * 64, g = blockIdx.y, tid = threadIdx.x;
    __shared__ float tile[64][65];
    const float* src = kc + (size_t)g * CCH * HDD;
#pragma unroll
    for (int r2 = 0; r2 < 16; r2++) {
        int sl = r2 * 4 + (tid >> 6), d2 = tid & 63;
        tile[sl][d2] = src[(size_t)(s0 + sl) * HDD + d2];
    }
    __syncthreads();
#pragma unroll
    for (int r2 = 0; r2 < 16; r2++) {
        int d2 = r2 * 4 + (tid >> 6), sl = tid & 63;
        kfT[((size_t)g * HDD + d2) * SEQ + s0 + sl] = tile[sl][d2];
    }
}

// -------- transpose V cache [g][d][s] -> vfull [g][s][d]  (cache part only) -----
__global__ __launch_bounds__(256) void build_vf(const float* __restrict__ vc,
                                                float* __restrict__ vf) {
    int s0 = blockIdx.x * 64, g = blockIdx.y, tid = threadIdx.x;
    __shared__ float tile[64][65];
    const float* src = vc + (size_t)g * HDD * CCH;
#pragma unroll
    for (int r2 = 0; r2 < 16; r2++) {
        int dl = r2 * 4 + (tid >> 6), sl = tid & 63;
        tile[dl][sl] = src[(size_t)dl * CCH + s0 + sl];
    }
    __syncthreads();
#pragma unroll
    for (int r2 = 0; r2 < 16; r2++) {
        int sl = r2 * 4 + (tid >> 6), dl = tid & 63;
        vf[((size_t)g * SEQ + s0 + sl) * HDD + dl] = tile[dl][sl];
    }
}

// ---------------- generic fp32 GEMM, 64x64 tile, BK=16, 4x4 microtile ----------
// C[m][n] (+)= sum_k A[m][k] * B[k][n]; grid = (M/64, N/64, heads*nsplit)
template <int ATOMIC>
__global__ __launch_bounds__(256) void gemm64(const float* __restrict__ A, int lda, size_t aHead,
                                              const float* __restrict__ B, int ldb, size_t bHead, int bdiv,
                                              float* __restrict__ C, int ldc, size_t cHead, int cOffPerHead,
                                              int kchunk, int nsplit) {
    int h = blockIdx.z / nsplit;
    int kz = blockIdx.z % nsplit;
    A += (size_t)h * aHead;
    B += (size_t)(h / bdiv) * bHead;
    C += (size_t)h * cHead + (size_t)h * cOffPerHead;
    int m0 = blockIdx.x * 64, n0 = blockIdx.y * 64;
    int kstart = kz * kchunk;
    __shared__ float As[16][64];
    __shared__ float Bs[16][64];
    int tid = threadIdx.x;
    int tx = tid & 15, ty = tid >> 4;
    const float* Ap = A + (size_t)(m0 + (tid >> 2)) * lda + kstart + (tid & 3) * 4;
    const float* Bp = B + (size_t)(kstart + (tid >> 4)) * ldb + n0 + (tid & 15) * 4;
    float acc[4][4] = {};
    for (int kc = 0; kc < kchunk; kc += 16) {
        float4 av = *(const float4*)Ap;
        float4 bv = *(const float4*)Bp;
        __syncthreads();
        int ak = (tid & 3) * 4, am = tid >> 2;
        As[ak + 0][am] = av.x;
        As[ak + 1][am] = av.y;
        As[ak + 2][am] = av.z;
        As[ak + 3][am] = av.w;
        *(float4*)&Bs[tid >> 4][(tid & 15) * 4] = bv;
        __syncthreads();
        Ap += 16;
        Bp += (size_t)16 * ldb;
#pragma unroll
        for (int kk = 0; kk < 16; kk++) {
            float4 a = *(const float4*)&As[kk][ty * 4];
            float4 b = *(const float4*)&Bs[kk][tx * 4];
            float aa[4] = {a.x, a.y, a.z, a.w};
            float bb[4] = {b.x, b.y, b.z, b.w};
#pragma unroll
            for (int j = 0; j < 4; j++)
#pragma unroll
                for (int l = 0; l < 4; l++) acc[j][l] = fmaf(aa[j], bb[l], acc[j][l]);
        }
    }
    float* Cp = C + (size_t)(m0 + ty * 4) * ldc + n0 + tx * 4;
    if (ATOMIC) {
#pragma unroll
        for (int j = 0; j < 4; j++)
#pragma unroll
            for (int l = 0; l < 4; l++) atomicAdd(&Cp[(size_t)j * ldc + l], acc[j][l]);
    } else {
#pragma unroll
        for (int j = 0; j < 4; j++) {
            float4 o = make_float4(acc[j][0], acc[j][1], acc[j][2], acc[j][3]);
            *(float4*)&Cp[(size_t)j * ldc] = o;
        }
    }
}

// ---------------- softcap + mask + softmax over S, per (head, t) row ----------
__global__ __launch_bounds__(256) void softcap_softmax(float* __restrict__ sc,
                                                       const float* __restrict__ mask) {
    int t = blockIdx.x, hh = blockIdx.y, tid = threadIdx.x;
    float* row = sc + ((size_t)hh * TT + t) * SEQ;
    const float* mrow = mask + (size_t)t * SEQ;
    float v[8];
    float mx = -1e30f;
#pragma unroll
    for (int k2 = 0; k2 < 8; k2++) {
        int s = tid + k2 * 256;
        float x = row[s] * 0.125f;           // * 1/sqrt(HD)
        x = 50.0f * fast_tanh(x * 0.02f);    // softcap
        x += mrow[s];
        v[k2] = x;
        mx = fmaxf(mx, x);
    }
#pragma unroll
    for (int o = 32; o > 0; o >>= 1) mx = fmaxf(mx, __shfl_xor(mx, o));
    __shared__ float red[4];
    if ((tid & 63) == 0) red[tid >> 6] = mx;
    __syncthreads();
    mx = fmaxf(fmaxf(red[0], red[1]), fmaxf(red[2], red[3]));
    float sum = 0.0f;
#pragma unroll
    for (int k2 = 0; k2 < 8; k2++) {
        v[k2] = __expf(v[k2] - mx);
        sum += v[k2];
    }
#pragma unroll
    for (int o = 32; o > 0; o >>= 1) sum += __shfl_xor(sum, o);
    __syncthreads();  // red[] reuse
    if ((tid & 63) == 0) red[tid >> 6] = sum;
    __syncthreads();
    sum = red[0] + red[1] + red[2] + red[3];
    float inv = 1.0f / sum;
#pragma unroll
    for (int k2 = 0; k2 < 8; k2++) row[tid + k2 * 256] = v[k2] * inv;
}

// ---------------- gate = gelu(gate) * up ----------------
__global__ __launch_bounds__(256) void gelu_mul_k(float* __restrict__ g,
                                                  const float* __restrict__ u) {
    size_t i = (size_t)blockIdx.x * 256 + threadIdx.x;
    float x = g[i];
    float inner = 0.7978845608028654f * (x + 0.044715f * x * x * x);
    g[i] = 0.5f * x * (1.0f + fast_tanh(inner)) * u[i];
}

// ---------------- zero a float4 region ----------------
__global__ __launch_bounds__(256) void zero4_k(float4* __restrict__ p) {
    p[(size_t)blockIdx.x * 256 + threadIdx.x] = make_float4(0.f, 0.f, 0.f, 0.f);
}

// ---------------- workspace offsets (floats) ----------------
#define OFF_H    0u
#define OFF_X    393216u
#define OFF_QKV  786432u
#define OFF_ATTN 1441792u
#define OFF_AO   1835008u
#define OFF_GATE 2228224u
#define OFF_UP   3276800u
#define OFF_FFO  4325376u
#define OFF_Q    4718592u
#define OFF_KFT  5111808u
#define OFF_VF   5636096u
#define OFF_SC   6160384u
// end: 18743296 floats (~75 MB)

extern "C" void kernel_launch(void* const* d_in, const int* in_sizes, int n_in,
                              void* d_out, int out_size, void* d_ws, size_t ws_size,
                              hipStream_t stream) {
    const float* emb          = (const float*)d_in[0];
    const float* kcache       = (const float*)d_in[1];
    const float* vcache       = (const float*)d_in[2];
    const float* pre_attn_w   = (const float*)d_in[3];
    const float* w_qkv        = (const float*)d_in[4];
    const float* q_norm_w     = (const float*)d_in[5];
    const float* k_norm_w     = (const float*)d_in[6];
    const float* w_out        = (const float*)d_in[7];
    const float* post_attn_w  = (const float*)d_in[8];
    const float* pre_ff_w     = (const float*)d_in[9];
    const float* w_gate       = (const float*)d_in[10];
    const float* w_up         = (const float*)d_in[11];
    const float* w_down       = (const float*)d_in[12];
    const float* post_ff_w    = (const float*)d_in[13];
    const float* final_norm_w = (const float*)d_in[14];
    const float* w_lm         = (const float*)d_in[15];
    const float* pe_cos       = (const float*)d_in[16];
    const float* pe_sin       = (const float*)d_in[17];
    const float* pel_cos      = (const float*)d_in[18];
    const float* pel_sin      = (const float*)d_in[19];
    const float* mask_g       = (const float*)d_in[20];
    const float* mask_l       = (const float*)d_in[21];

    float* ws   = (float*)d_ws;
    float* h    = ws + OFF_H;
    float* x    = ws + OFF_X;
    float* qkv  = ws + OFF_QKV;
    float* attn = ws + OFF_ATTN;
    float* ao   = ws + OFF_AO;
    float* gate = ws + OFF_GATE;
    float* up   = ws + OFF_UP;
    float* ffo  = ws + OFF_FFO;
    float* q    = ws + OFF_Q;
    float* kfT  = ws + OFF_KFT;
    float* vf   = ws + OFF_VF;
    float* sc   = ws + OFF_SC;
    float* out  = (float*)d_out;

    // h = embeddings
    hipMemcpyAsync(h, emb, (size_t)TT * DD * sizeof(float), hipMemcpyDeviceToDevice, stream);

    for (int i = 0; i < NL; i++) {
        bool is_local = ((i + 1) % 6 == 0);
        const float* cosp  = is_local ? pel_cos : pe_cos;
        const float* sinp  = is_local ? pel_sin : pe_sin;
        const float* maskp = is_local ? mask_l : mask_g;
        const float* wqkv_i  = w_qkv  + (size_t)i * DD * 1280;
        const float* wout_i  = w_out  + (size_t)i * DD * DD;
        const float* wgate_i = w_gate + (size_t)i * DD * FFF;
        const float* wup_i   = w_up   + (size_t)i * DD * FFF;
        const float* wdown_i = w_down + (size_t)i * FFF * DD;
        const float* kc_i = kcache + (size_t)i * NGG * CCH * HDD;
        const float* vc_i = vcache + (size_t)i * NGG * HDD * CCH;

        // zero atomic-accum region: qkv..ffo (3,932,160 floats = 983,040 float4)
        zero4_k<<<3840, 256, 0, stream>>>((float4*)(ws + OFF_QKV));

        // pre-attn norm
        rmsnorm_k<<<TT, 256, 0, stream>>>(h, pre_attn_w + (size_t)i * DD, x);

        // qkv = x @ w_qkv  (M=512, N=1280, K=768, splitK=2)
        gemm64<1><<<dim3(8, 20, 2), 256, 0, stream>>>(x, DD, 0, wqkv_i, 1280, 0, 1,
                                                      qkv, 1280, 0, 0, 384, 2);

        // build transposed caches
        build_kT<<<dim3(24, 4), 256, 0, stream>>>(kc_i, kfT);
        build_vf<<<dim3(24, 4), 256, 0, stream>>>(vc_i, vf);

        // per-head norm + rope + scatter (also fills new part of kfT/vf)
        qkv_post<<<2560, 256, 0, stream>>>(qkv, q_norm_w + (size_t)i * HDD,
                                           k_norm_w + (size_t)i * HDD, cosp, sinp,
                                           q, kfT, vf);

        // scores[h] = q[h] @ kT[g]   (M=512, N=2048, K=64), grid.z = 12 heads
        gemm64<0><<<dim3(8, 32, 12), 256, 0, stream>>>(
            q, HDD, (size_t)TT * HDD, kfT, SEQ, (size_t)HDD * SEQ, 3,
            sc, SEQ, (size_t)TT * SEQ, 0, 64, 1);

        // softcap + mask + softmax
        softcap_softmax<<<dim3(TT, NHH), 256, 0, stream>>>(sc, maskp);

        // attn[:, h*64:(h+1)*64] += probs[h] @ vfull[g]   (M=512,N=64,K=2048, splitK=8)
        gemm64<1><<<dim3(8, 1, NHH * 8), 256, 0, stream>>>(
            sc, SEQ, (size_t)TT * SEQ, vf, HDD, (size_t)SEQ * HDD, 3,
            attn, DD, 0, 64, 256, 8);

        // ao = attn @ w_out  (M=512,N=768,K=768, splitK=4)
        gemm64<1><<<dim3(8, 12, 4), 256, 0, stream>>>(attn, DD, 0, wout_i, DD, 0, 1,
                                                      ao, DD, 0, 0, 192, 4);

        // h += rmsnorm(ao, post_attn_w)
        addnorm_k<<<TT, 256, 0, stream>>>(h, ao, post_attn_w + (size_t)i * DD);

        // FF
        rmsnorm_k<<<TT, 256, 0, stream>>>(h, pre_ff_w + (size_t)i * DD, x);
        gemm64<1><<<dim3(8, 32, 2), 256, 0, stream>>>(x, DD, 0, wgate_i, FFF, 0, 1,
                                                      gate, FFF, 0, 0, 384, 2);
        gemm64<1><<<dim3(8, 32, 2), 256, 0, stream>>>(x, DD, 0, wup_i, FFF, 0, 1,
                                                      up, FFF, 0, 0, 384, 2);
        gelu_mul_k<<<4096, 256, 0, stream>>>(gate, up);
        gemm64<1><<<dim3(8, 12, 8), 256, 0, stream>>>(gate, FFF, 0, wdown_i, DD, 0, 1,
                                                      ffo, DD, 0, 0, 256, 8);
        addnorm_k<<<TT, 256, 0, stream>>>(h, ffo, post_ff_w + (size_t)i * DD);
    }

    // final norm + lm head (M=512, N=32000, K=768)
    rmsnorm_k<<<TT, 256, 0, stream>>>(h, final_norm_w, x);
    gemm64<0><<<dim3(8, 500, 1), 256, 0, stream>>>(x, DD, 0, w_lm, VOC, 0, 1,
                                                   out, VOC, 0, 0, 768, 1);
}

// Round 2
// 4496.607 us; speedup vs baseline: 2.3724x; 2.3724x over previous
//
#include <hip/hip_runtime.h>
#include <math.h>

#define TT 512
#define DD 768
#define NHH 12
#define NGG 4
#define HDD 64
#define FFF 2048
#define CCH 1536
#define SEQ 2048
#define NL 26
#define VOC 32000

typedef short bh8 __attribute__((ext_vector_type(8)));
typedef float f32x4 __attribute__((ext_vector_type(4)));

__device__ __forceinline__ float fast_tanh(float x) {
    float e = __expf(2.0f * x);
    return 1.0f - 2.0f / (e + 1.0f);
}

// fp32 -> bf16 (RNE) as raw short
__device__ __forceinline__ short f2bf(float f) {
    union { float f; unsigned u; } v;
    v.f = f;
    unsigned r = v.u + 0x7fffu + ((v.u >> 16) & 1u);
    return (short)(r >> 16);
}

struct __align__(8) S4 { short v[4]; };
struct __align__(16) S8 { short v[8]; };

// ---------------- rmsnorm: out = rms_norm(in, w) ----------------
__global__ __launch_bounds__(256) void rmsnorm_k(const float* __restrict__ in,
                                                 const float* __restrict__ w,
                                                 float* __restrict__ out) {
    int t = blockIdx.x, tid = threadIdx.x;
    const float* row = in + (size_t)t * DD;
    float x0 = row[tid], x1 = row[tid + 256], x2 = row[tid + 512];
    float s = x0 * x0 + x1 * x1 + x2 * x2;
#pragma unroll
    for (int o = 32; o > 0; o >>= 1) s += __shfl_xor(s, o);
    __shared__ float red[4];
    if ((tid & 63) == 0) red[tid >> 6] = s;
    __syncthreads();
    s = red[0] + red[1] + red[2] + red[3];
    float r = rsqrtf(s / 768.0f + 1e-6f);
    float* orow = out + (size_t)t * DD;
    orow[tid]       = x0 * r * (1.0f + w[tid]);
    orow[tid + 256] = x1 * r * (1.0f + w[tid + 256]);
    orow[tid + 512] = x2 * r * (1.0f + w[tid + 512]);
}

// ---------------- addnorm: h += rms_norm(in, w) ----------------
__global__ __launch_bounds__(256) void addnorm_k(float* __restrict__ h,
                                                 const float* __restrict__ in,
                                                 const float* __restrict__ w) {
    int t = blockIdx.x, tid = threadIdx.x;
    const float* row = in + (size_t)t * DD;
    float x0 = row[tid], x1 = row[tid + 256], x2 = row[tid + 512];
    float s = x0 * x0 + x1 * x1 + x2 * x2;
#pragma unroll
    for (int o = 32; o > 0; o >>= 1) s += __shfl_xor(s, o);
    __shared__ float red[4];
    if ((tid & 63) == 0) red[tid >> 6] = s;
    __syncthreads();
    s = red[0] + red[1] + red[2] + red[3];
    float r = rsqrtf(s / 768.0f + 1e-6f);
    float* hrow = h + (size_t)t * DD;
    hrow[tid]       += x0 * r * (1.0f + w[tid]);
    hrow[tid + 256] += x1 * r * (1.0f + w[tid + 256]);
    hrow[tid + 512] += x2 * r * (1.0f + w[tid + 512]);
}

// ---- weight transpose+convert: w [K][N] fp32 -> wT [N][K] bf16. grid (N/64,K/64,1|2)
__global__ __launch_bounds__(256) void wtrans(const float* __restrict__ w0, short* __restrict__ o0,
                                              const float* __restrict__ w1, short* __restrict__ o1,
                                              int N, int K) {
    const float* w = blockIdx.z ? w1 : w0;
    short* o = blockIdx.z ? o1 : o0;
    int n0 = blockIdx.x * 64, k0 = blockIdx.y * 64;
    __shared__ short t[64][72];
    int tid = threadIdx.x;
#pragma unroll
    for (int it = 0; it < 4; it++) {
        int kr = (tid >> 4) + it * 16, nc = (tid & 15) * 4;
        float4 v = *(const float4*)&w[(size_t)(k0 + kr) * N + n0 + nc];
        S4 p; p.v[0] = f2bf(v.x); p.v[1] = f2bf(v.y); p.v[2] = f2bf(v.z); p.v[3] = f2bf(v.w);
        *(S4*)&t[kr][nc] = p;
    }
    __syncthreads();
#pragma unroll
    for (int it = 0; it < 2; it++) {
        int nr = tid >> 2, kb2 = (tid & 3) * 16 + it * 8;
        S8 p;
#pragma unroll
        for (int j = 0; j < 8; j++) p.v[j] = t[kb2 + j][nr];
        *(S8*)&o[(size_t)(n0 + nr) * K + k0 + kb2] = p;
    }
}

// ---- convert KV caches to bf16 (K: [g][s][d] straight; V: [g][d][s] straight) ----
__global__ __launch_bounds__(256) void cvt_kv(const float* __restrict__ kc,
                                              const float* __restrict__ vc,
                                              short* __restrict__ kb,
                                              short* __restrict__ vb) {
    int idx = blockIdx.x * 256 + threadIdx.x;
    if (idx < 98304) {
        int e = idx * 4;
        int g = e / 98304, off = e % 98304;
        float4 v = *(const float4*)&kc[(size_t)g * 98304 + off];
        S4 p; p.v[0] = f2bf(v.x); p.v[1] = f2bf(v.y); p.v[2] = f2bf(v.z); p.v[3] = f2bf(v.w);
        *(S4*)&kb[(size_t)g * (SEQ * HDD) + off] = p;
    } else {
        int e = (idx - 98304) * 4;
        int row = e / CCH, c = e % CCH;
        float4 v = *(const float4*)&vc[(size_t)row * CCH + c];
        S4 p; p.v[0] = f2bf(v.x); p.v[1] = f2bf(v.y); p.v[2] = f2bf(v.z); p.v[3] = f2bf(v.w);
        *(S4*)&vb[(size_t)row * SEQ + c] = p;
    }
}

// ------- qkv post: per-head rmsnorm (q,k) + rope, scatter q16 / kb / vb (bf16) -------
__global__ __launch_bounds__(256) void qkv_post(const float* __restrict__ qkv,
                                                const float* __restrict__ qnw,
                                                const float* __restrict__ knw,
                                                const float* __restrict__ cosp,
                                                const float* __restrict__ sinp,
                                                short* __restrict__ q16,
                                                short* __restrict__ kb,
                                                short* __restrict__ vb) {
    int tid = threadIdx.x;
    int lane = tid & 63, wid = tid >> 6;
    int sg = blockIdx.x * 4 + wid;
    int t = sg / 20, slot = sg % 20;
    int g = slot / 5, r = slot % 5;
    float v = qkv[(size_t)t * 1280 + slot * 64 + lane];
    if (r == 4) {
        vb[((size_t)g * HDD + lane) * SEQ + CCH + t] = f2bf(v);
        return;
    }
    float s = v * v;
#pragma unroll
    for (int o = 32; o > 0; o >>= 1) s += __shfl_xor(s, o);
    float nv = v * rsqrtf(s / 64.0f + 1e-6f);
    const float* wn = (r < 3) ? qnw : knw;
    nv *= (1.0f + wn[lane]);
    float other = __shfl_xor(nv, 32);
    float rot = (lane < 32) ? -other : other;
    float ov = nv * cosp[t * 64 + lane] + rot * sinp[t * 64 + lane];
    if (r < 3)
        q16[(((size_t)(g * 3 + r)) * TT + t) * HDD + lane] = f2bf(ov);
    else
        kb[((size_t)g * SEQ + CCH + t) * HDD + lane] = f2bf(ov);
}

// ---------------- bf16 MFMA GEMM: C[m][n] (+)= A[m][k] * Bt[n][k] ----------------
// 64x64 tile, BK=32, 256 threads = 4 waves, each wave one 32x32 quadrant.
template <int A_BF16, int ATOMIC>
__global__ __launch_bounds__(256) void mgemm(const void* __restrict__ Av, int lda, unsigned long long aHead,
                                             const short* __restrict__ Bt, int ldb, unsigned long long bHead, int bdiv,
                                             float* __restrict__ C, int ldc, unsigned long long cHead, int cOff,
                                             int kchunk, int nsplit) {
    int h = blockIdx.z / nsplit, kz = blockIdx.z % nsplit;
    const char* Abase = (const char*)Av + (size_t)h * aHead * (A_BF16 ? 2 : 4);
    Bt += (size_t)(h / bdiv) * bHead;
    C += (size_t)h * cHead + (size_t)h * cOff;

    __shared__ short As[64][40];
    __shared__ short Bs[64][40];

    int tid = threadIdx.x;
    int srow = tid >> 2, skp = (tid & 3) * 8;
    int m0 = blockIdx.x * 64, n0 = blockIdx.y * 64;
    int kbase = kz * kchunk;
    int lane = tid & 63, wid = tid >> 6;
    int mq = (wid >> 1) * 32, nq = (wid & 1) * 32;
    int frow = lane & 15, fk = (lane >> 4) * 8;

    f32x4 acc00 = {}, acc01 = {}, acc10 = {}, acc11 = {};

    const short* Bp = Bt + (size_t)(n0 + srow) * ldb + kbase + skp;

    for (int kc = 0; kc < kchunk; kc += 32) {
        bh8 a8, b8;
        b8 = *(const bh8*)Bp;
        Bp += 32;
        if (A_BF16) {
            const short* ap = (const short*)Abase + (size_t)(m0 + srow) * lda + kbase + kc + skp;
            a8 = *(const bh8*)ap;
        } else {
            const float* ap = (const float*)Abase + (size_t)(m0 + srow) * lda + kbase + kc + skp;
            float4 x1 = *(const float4*)ap;
            float4 x2 = *(const float4*)(ap + 4);
            a8[0] = f2bf(x1.x); a8[1] = f2bf(x1.y); a8[2] = f2bf(x1.z); a8[3] = f2bf(x1.w);
            a8[4] = f2bf(x2.x); a8[5] = f2bf(x2.y); a8[6] = f2bf(x2.z); a8[7] = f2bf(x2.w);
        }
        __syncthreads();
        *(bh8*)&As[srow][skp] = a8;
        *(bh8*)&Bs[srow][skp] = b8;
        __syncthreads();
        bh8 a0 = *(const bh8*)&As[mq + frow][fk];
        bh8 a1 = *(const bh8*)&As[mq + 16 + frow][fk];
        bh8 b0 = *(const bh8*)&Bs[nq + frow][fk];
        bh8 b1 = *(const bh8*)&Bs[nq + 16 + frow][fk];
        acc00 = __builtin_amdgcn_mfma_f32_16x16x32_bf16(a0, b0, acc00, 0, 0, 0);
        acc01 = __builtin_amdgcn_mfma_f32_16x16x32_bf16(a0, b1, acc01, 0, 0, 0);
        acc10 = __builtin_amdgcn_mfma_f32_16x16x32_bf16(a1, b0, acc10, 0, 0, 0);
        acc11 = __builtin_amdgcn_mfma_f32_16x16x32_bf16(a1, b1, acc11, 0, 0, 0);
    }

    int er = (lane >> 4) * 4, ec = lane & 15;
    int grow = m0 + mq + er, gcol = n0 + nq + ec;
#pragma unroll
    for (int r = 0; r < 4; r++) {
        float v00 = acc00[r], v01 = acc01[r], v10 = acc10[r], v11 = acc11[r];
        size_t r0 = (size_t)(grow + r) * ldc, r1 = (size_t)(grow + 16 + r) * ldc;
        if (ATOMIC) {
            atomicAdd(&C[r0 + gcol], v00);
            atomicAdd(&C[r0 + gcol + 16], v01);
            atomicAdd(&C[r1 + gcol], v10);
            atomicAdd(&C[r1 + gcol + 16], v11);
        } else {
            C[r0 + gcol] = v00;
            C[r0 + gcol + 16] = v01;
            C[r1 + gcol] = v10;
            C[r1 + gcol + 16] = v11;
        }
    }
}

// ---------------- softcap + mask + softmax; fp32 scores in, bf16 probs out ----------
__global__ __launch_bounds__(256) void softcap_softmax(const float* __restrict__ sc,
                                                       const float* __restrict__ mask,
                                                       short* __restrict__ pb) {
    int t = blockIdx.x, hh = blockIdx.y, tid = threadIdx.x;
    const float* row = sc + ((size_t)hh * TT + t) * SEQ;
    const float* mrow = mask + (size_t)t * SEQ;
    float v[8];
    float mx = -1e30f;
#pragma unroll
    for (int k2 = 0; k2 < 8; k2++) {
        int s = tid + k2 * 256;
        float x = row[s] * 0.125f;
        x = 50.0f * fast_tanh(x * 0.02f);
        x += mrow[s];
        v[k2] = x;
        mx = fmaxf(mx, x);
    }
#pragma unroll
    for (int o = 32; o > 0; o >>= 1) mx = fmaxf(mx, __shfl_xor(mx, o));
    __shared__ float red[4];
    if ((tid & 63) == 0) red[tid >> 6] = mx;
    __syncthreads();
    mx = fmaxf(fmaxf(red[0], red[1]), fmaxf(red[2], red[3]));
    float sum = 0.0f;
#pragma unroll
    for (int k2 = 0; k2 < 8; k2++) {
        v[k2] = __expf(v[k2] - mx);
        sum += v[k2];
    }
#pragma unroll
    for (int o = 32; o > 0; o >>= 1) sum += __shfl_xor(sum, o);
    __syncthreads();
    if ((tid & 63) == 0) red[tid >> 6] = sum;
    __syncthreads();
    sum = red[0] + red[1] + red[2] + red[3];
    float inv = 1.0f / sum;
    short* prow = pb + ((size_t)hh * TT + t) * SEQ;
#pragma unroll
    for (int k2 = 0; k2 < 8; k2++) prow[tid + k2 * 256] = f2bf(v[k2] * inv);
}

// ---------------- gact = gelu(gate) * up (bf16 out) ----------------
__global__ __launch_bounds__(256) void gelu_mul_k(const float* __restrict__ g,
                                                  const float* __restrict__ u,
                                                  short* __restrict__ o) {
    size_t i = (size_t)blockIdx.x * 256 + threadIdx.x;
    float x = g[i];
    float inner = 0.7978845608028654f * (x + 0.044715f * x * x * x);
    o[i] = f2bf(0.5f * x * (1.0f + fast_tanh(inner)) * u[i]);
}

// ---------------- zero a float4 region ----------------
__global__ __launch_bounds__(256) void zero4_k(float4* __restrict__ p) {
    p[(size_t)blockIdx.x * 256 + threadIdx.x] = make_float4(0.f, 0.f, 0.f, 0.f);
}

// ---------------- workspace offsets ----------------
// fp32 region (floats)
#define OFF_H    0u
#define OFF_X    393216u
#define OFF_QKV  786432u
#define OFF_ATTN 1441792u
#define OFF_AO   1835008u
#define OFF_FFO  2228224u
#define OFF_GATE 2621440u
#define OFF_UP   3670016u
#define OFF_SC   4718592u
#define F32_END  17301504u
// bf16 region (shorts, from bws)
#define BO_Q16   0u
#define BO_KB    393216u
#define BO_VB    917504u
#define BO_PB    1441792u
#define BO_GACT  14024704u
#define BO_WQ    15073280u
#define BO_WO    16056320u
#define BO_WG    16646144u
#define BO_WU    18219008u
#define BO_WD    19791872u
#define BO_LMT   21364736u
// end: 45940736 shorts; total ws ~161 MB

extern "C" void kernel_launch(void* const* d_in, const int* in_sizes, int n_in,
                              void* d_out, int out_size, void* d_ws, size_t ws_size,
                              hipStream_t stream) {
    const float* emb          = (const float*)d_in[0];
    const float* kcache       = (const float*)d_in[1];
    const float* vcache       = (const float*)d_in[2];
    const float* pre_attn_w   = (const float*)d_in[3];
    const float* w_qkv        = (const float*)d_in[4];
    const float* q_norm_w     = (const float*)d_in[5];
    const float* k_norm_w     = (const float*)d_in[6];
    const float* w_out        = (const float*)d_in[7];
    const float* post_attn_w  = (const float*)d_in[8];
    const float* pre_ff_w     = (const float*)d_in[9];
    const float* w_gate       = (const float*)d_in[10];
    const float* w_up         = (const float*)d_in[11];
    const float* w_down       = (const float*)d_in[12];
    const float* post_ff_w    = (const float*)d_in[13];
    const float* final_norm_w = (const float*)d_in[14];
    const float* w_lm         = (const float*)d_in[15];
    const float* pe_cos       = (const float*)d_in[16];
    const float* pe_sin       = (const float*)d_in[17];
    const float* pel_cos      = (const float*)d_in[18];
    const float* pel_sin      = (const float*)d_in[19];
    const float* mask_g       = (const float*)d_in[20];
    const float* mask_l       = (const float*)d_in[21];

    float* ws   = (float*)d_ws;
    float* h    = ws + OFF_H;
    float* x    = ws + OFF_X;
    float* qkv  = ws + OFF_QKV;
    float* attn = ws + OFF_ATTN;
    float* ao   = ws + OFF_AO;
    float* ffo  = ws + OFF_FFO;
    float* gate = ws + OFF_GATE;
    float* up   = ws + OFF_UP;
    float* sc   = ws + OFF_SC;
    short* bws  = (short*)(ws + F32_END);
    short* q16  = bws + BO_Q16;
    short* kb   = bws + BO_KB;
    short* vb   = bws + BO_VB;
    short* pb   = bws + BO_PB;
    short* gact = bws + BO_GACT;
    short* wqT  = bws + BO_WQ;
    short* woT  = bws + BO_WO;
    short* wgT  = bws + BO_WG;
    short* wuT  = bws + BO_WU;
    short* wdT  = bws + BO_WD;
    short* lmT  = bws + BO_LMT;
    float* out  = (float*)d_out;

    hipMemcpyAsync(h, emb, (size_t)TT * DD * sizeof(float), hipMemcpyDeviceToDevice, stream);

    for (int i = 0; i < NL; i++) {
        bool is_local = ((i + 1) % 6 == 0);
        const float* cosp  = is_local ? pel_cos : pe_cos;
        const float* sinp  = is_local ? pel_sin : pe_sin;
        const float* maskp = is_local ? mask_l : mask_g;
        const float* wqkv_i  = w_qkv  + (size_t)i * DD * 1280;
        const float* wout_i  = w_out  + (size_t)i * DD * DD;
        const float* wgate_i = w_gate + (size_t)i * DD * FFF;
        const float* wup_i   = w_up   + (size_t)i * DD * FFF;
        const float* wdown_i = w_down + (size_t)i * FFF * DD;
        const float* kc_i = kcache + (size_t)i * NGG * CCH * HDD;
        const float* vc_i = vcache + (size_t)i * NGG * HDD * CCH;

        // zero atomic-accum buffers attn/ao/ffo (contiguous, 294912 float4)
        zero4_k<<<1152, 256, 0, stream>>>((float4*)(ws + OFF_ATTN));

        // pre-attn norm
        rmsnorm_k<<<TT, 256, 0, stream>>>(h, pre_attn_w + (size_t)i * DD, x);

        // transpose+convert qkv weights: [768][1280] -> [1280][768] bf16
        wtrans<<<dim3(20, 12, 1), 256, 0, stream>>>(wqkv_i, wqT, wqkv_i, wqT, 1280, DD);

        // qkv = x @ w_qkv  (M=512,N=1280,K=768)
        mgemm<0, 0><<<dim3(8, 20, 1), 256, 0, stream>>>(x, DD, 0ull, wqT, DD, 0ull, 1,
                                                        qkv, 1280, 0ull, 0, 768, 1);

        // convert KV caches to bf16 (natural layouts are already B^T)
        cvt_kv<<<768, 256, 0, stream>>>(kc_i, vc_i, kb, vb);

        // per-head norm + rope; fills q16, and new rows of kb / cols of vb
        qkv_post<<<2560, 256, 0, stream>>>(qkv, q_norm_w + (size_t)i * HDD,
                                           k_norm_w + (size_t)i * HDD, cosp, sinp,
                                           q16, kb, vb);

        // transpose+convert w_out: [768][768] -> bf16
        wtrans<<<dim3(12, 12, 1), 256, 0, stream>>>(wout_i, woT, wout_i, woT, DD, DD);

        // scores[h] = q16[h] @ kb[g]^T  (M=512,N=2048,K=64)
        mgemm<1, 0><<<dim3(8, 32, 12), 256, 0, stream>>>(
            q16, HDD, (unsigned long long)(TT * HDD), kb, HDD,
            (unsigned long long)(SEQ * HDD), 3, sc, SEQ,
            (unsigned long long)(TT * SEQ), 0, 64, 1);

        // softcap + mask + softmax -> bf16 probs
        softcap_softmax<<<dim3(TT, NHH), 256, 0, stream>>>(sc, maskp, pb);

        // attn[:, h*64:] += probs[h] @ vb[g]^T  (M=512,N=64,K=2048, splitK=4)
        mgemm<1, 1><<<dim3(8, 1, NHH * 4), 256, 0, stream>>>(
            pb, SEQ, (unsigned long long)(TT * SEQ), vb, SEQ,
            (unsigned long long)(HDD * SEQ), 3, attn, DD, 0ull, 64, 512, 4);

        // ao = attn @ w_out  (M=512,N=768,K=768, splitK=2)
        mgemm<0, 1><<<dim3(8, 12, 2), 256, 0, stream>>>(attn, DD, 0ull, woT, DD, 0ull, 1,
                                                        ao, DD, 0ull, 0, 384, 2);

        addnorm_k<<<TT, 256, 0, stream>>>(h, ao, post_attn_w + (size_t)i * DD);

        // FF
        rmsnorm_k<<<TT, 256, 0, stream>>>(h, pre_ff_w + (size_t)i * DD, x);
        wtrans<<<dim3(32, 12, 2), 256, 0, stream>>>(wgate_i, wgT, wup_i, wuT, FFF, DD);
        mgemm<0, 0><<<dim3(8, 32, 1), 256, 0, stream>>>(x, DD, 0ull, wgT, DD, 0ull, 1,
                                                        gate, FFF, 0ull, 0, 768, 1);
        mgemm<0, 0><<<dim3(8, 32, 1), 256, 0, stream>>>(x, DD, 0ull, wuT, DD, 0ull, 1,
                                                        up, FFF, 0ull, 0, 768, 1);
        gelu_mul_k<<<4096, 256, 0, stream>>>(gate, up, gact);
        wtrans<<<dim3(12, 32, 1), 256, 0, stream>>>(wdown_i, wdT, wdown_i, wdT, DD, FFF);
        mgemm<1, 1><<<dim3(8, 12, 4), 256, 0, stream>>>(gact, FFF, 0ull, wdT, FFF, 0ull, 1,
                                                        ffo, DD, 0ull, 0, 512, 4);
        addnorm_k<<<TT, 256, 0, stream>>>(h, ffo, post_ff_w + (size_t)i * DD);
    }

    // final norm + lm head
    rmsnorm_k<<<TT, 256, 0, stream>>>(h, final_norm_w, x);
    wtrans<<<dim3(500, 12, 1), 256, 0, stream>>>(w_lm, lmT, w_lm, lmT, VOC, DD);
    mgemm<0, 0><<<dim3(8, 500, 1), 256, 0, stream>>>(x, DD, 0ull, lmT, DD, 0ull, 1,
                                                     out, VOC, 0ull, 0, 768, 1);
}